// Round 3
// baseline (935.428 us; speedup 1.0000x reference)
//
#include <hip/hip_runtime.h>
#include <hip/hip_bf16.h>
#include <hip/hip_fp16.h>

#define H 2048
#define E 8
#define DFF 8192
#define NTOK 4096
#define NB 4  // H/512 scale blocks

typedef _Float16 f16x8 __attribute__((ext_vector_type(8)));
typedef float f32x4 __attribute__((ext_vector_type(4)));

#define AS1 __attribute__((address_space(1)))
#define AS3 __attribute__((address_space(3)))

__device__ __forceinline__ void gl_lds16(const void* g, void* l) {
    __builtin_amdgcn_global_load_lds((const AS1 unsigned int*)g,
                                     (AS3 unsigned int*)l, 16, 0, 0);
}

__device__ __forceinline__ float gelu_f(float x) {
    // jax.nn.gelu approximate=True (tanh)
    float u = 0.7978845608028654f * x * (1.0f + 0.044715f * x * x);
    return 0.5f * x * (1.0f + tanhf(u));
}

// ---------------- router (fp32) + x -> fp16 cast ----------------
__global__ __launch_bounds__(256) void router_cast_kernel(
    const float* __restrict__ x, const float* __restrict__ rw,
    float* __restrict__ probs, _Float16* __restrict__ xh)
{
    int n = blockIdx.x, t = threadIdx.x;
    float acc[E];
#pragma unroll
    for (int e = 0; e < E; ++e) acc[e] = 0.f;
    const float* xr = x + (size_t)n * H;
#pragma unroll
    for (int k = 0; k < H / 256; ++k) {
        int h = t + k * 256;
        float xv = xr[h];
        xh[(size_t)n * H + h] = (_Float16)xv;
        const float4* r4 = reinterpret_cast<const float4*>(rw + (size_t)h * E);
        float4 a = r4[0], b = r4[1];
        acc[0] += xv * a.x; acc[1] += xv * a.y; acc[2] += xv * a.z; acc[3] += xv * a.w;
        acc[4] += xv * b.x; acc[5] += xv * b.y; acc[6] += xv * b.z; acc[7] += xv * b.w;
    }
#pragma unroll
    for (int e = 0; e < E; ++e) {
        float v = acc[e];
#pragma unroll
        for (int o = 32; o > 0; o >>= 1) v += __shfl_down(v, o, 64);
        acc[e] = v;
    }
    __shared__ float red[4][E];
    int wave = t >> 6, lane = t & 63;
    if (lane == 0) {
#pragma unroll
        for (int e = 0; e < E; ++e) red[wave][e] = acc[e];
    }
    __syncthreads();
    if (t == 0) {
        float lg[E];
        float mx = -1e30f;
#pragma unroll
        for (int e = 0; e < E; ++e) {
            lg[e] = red[0][e] + red[1][e] + red[2][e] + red[3][e];
            mx = fmaxf(mx, lg[e]);
        }
        float s = 0.f;
#pragma unroll
        for (int e = 0; e < E; ++e) { lg[e] = expf(lg[e] - mx); s += lg[e]; }
        float inv = 1.f / s;
#pragma unroll
        for (int e = 0; e < E; ++e) {
            float p = lg[e] * inv;
            p = __half2float(__float2half(p));  // fp16 round-trip as in reference
            probs[(size_t)n * E + e] = p;
        }
    }
}

// ---------------- transpose + cast fp32 [R,C] -> fp16 [C,R] ----------------
__global__ __launch_bounds__(256) void transpose_cast_kernel(
    const float* __restrict__ src, _Float16* __restrict__ dst, int R, int C)
{
    __shared__ float tile[32][33];
    int tx = threadIdx.x & 31, ty = threadIdx.x >> 5;
    int c0 = blockIdx.x * 32, r0 = blockIdx.y * 32;
#pragma unroll
    for (int i = ty; i < 32; i += 8)
        tile[i][tx] = src[(size_t)(r0 + i) * C + c0 + tx];
    __syncthreads();
#pragma unroll
    for (int i = ty; i < 32; i += 8)
        dst[(size_t)(c0 + i) * R + r0 + tx] = (_Float16)tile[tx][i];
}

// ---------------- NF4 dequant + expert mix -> moe (fp32) ----------------
__global__ __launch_bounds__(256) void moe_kernel(
    const int* __restrict__ nf4, const float* __restrict__ mean,
    const float* __restrict__ stdv, const float* __restrict__ cb,
    const float* __restrict__ probs, float* __restrict__ moe)
{
    int n = blockIdx.x, t = threadIdx.x;
    __shared__ float cbl[32];       // 2 copies of 16-entry codebook
    __shared__ float ps[E][NB];     // prob*std
    __shared__ float cmean[NB];     // sum_e prob*mean
    if (t < 16) { float v = cb[t]; cbl[t] = v; cbl[t + 16] = v; }
    else if (t >= 32 && t < 64) {
        int e = (t - 32) >> 2, b = t & 3;
        ps[e][b] = probs[(size_t)n * E + e] * stdv[((size_t)n * E + e) * NB + b];
    } else if (t >= 64 && t < 68) {
        int b = t - 64; float s = 0.f;
        for (int e = 0; e < E; ++e)
            s += probs[(size_t)n * E + e] * mean[((size_t)n * E + e) * NB + b];
        cmean[b] = s;
    }
    __syncthreads();
    int cboff = (t & 1) << 4;
    const int* w = nf4 + (size_t)n * (E * H / 2);
    float2* outp = reinterpret_cast<float2*>(moe + (size_t)n * H);
#pragma unroll
    for (int k = 0; k < 4; ++k) {    // b = (t + k*256)>>8 == k (wave-uniform)
        int j = t + k * 256;
        float psr[E];
#pragma unroll
        for (int e = 0; e < E; ++e) psr[e] = ps[e][k];
        float cm = cmean[k];
        float aL = cm, aH = cm;
#pragma unroll
        for (int e = 0; e < E; ++e) {
            int word = w[e * (H / 2) + j];
            aL += psr[e] * cbl[(word & 15) + cboff];
            aH += psr[e] * cbl[((word >> 4) & 15) + cboff];
        }
        outp[j] = make_float2(aL, aH);
    }
}

// ---------------- fp16 MFMA GEMM: C = A[M,K] * Bt[N,K]^T ----------------
// EPI 0: out = f16(gelu(acc))        (hidden, ld=N, OT=_Float16)
// EPI 1: out = acc + addsrc          (final, ld=N, OT=float)
template <int EPI, typename OT>
__global__ __launch_bounds__(256) void gemm_bt_kernel(
    const _Float16* __restrict__ A, const _Float16* __restrict__ Bt,
    const float* __restrict__ addsrc, OT* __restrict__ outb,
    int K, int N)
{
    __shared__ uint4 lds_u4[1024];   // 16 KB: A-tile [0,8192), B-tile [8192,16384)
    char* lds = (char*)lds_u4;

    int t = threadIdx.x;
    int m0 = blockIdx.y * 128, n0 = blockIdx.x * 128;
    int r = t & 127, s0 = t >> 7;            // staging row / k-seg
    const unsigned short* pA = (const unsigned short*)A + (size_t)(m0 + r) * K + s0 * 8;
    const unsigned short* pB = (const unsigned short*)Bt + (size_t)(n0 + r) * K + s0 * 8;
    unsigned dst0 = (unsigned)t * 16, dst1 = (unsigned)t * 16 + 4096;

    int lane = t & 63, wave = t >> 6;
    int wm = (wave & 1) * 64, wn = (wave >> 1) * 64;
    int q = lane >> 4, m16 = lane & 15;

    unsigned aoff[4], boff[4];
#pragma unroll
    for (int i = 0; i < 4; ++i) aoff[i] = (unsigned)(q * 128 + wm + i * 16 + m16) * 16;
#pragma unroll
    for (int j = 0; j < 4; ++j) boff[j] = 8192u + (unsigned)(q * 128 + wn + j * 16 + m16) * 16;

    f32x4 acc[4][4] = {};

    for (int k0 = 0; k0 < K; k0 += 32) {
        gl_lds16(pA + k0,      lds + dst0);
        gl_lds16(pA + k0 + 16, lds + dst1);
        gl_lds16(pB + k0,      lds + 8192 + dst0);
        gl_lds16(pB + k0 + 16, lds + 8192 + dst1);
        __syncthreads();
        f16x8 af[4], bfr[4];
#pragma unroll
        for (int i = 0; i < 4; ++i) af[i] = *(const f16x8*)(lds + aoff[i]);
#pragma unroll
        for (int j = 0; j < 4; ++j) bfr[j] = *(const f16x8*)(lds + boff[j]);
#pragma unroll
        for (int i = 0; i < 4; ++i)
#pragma unroll
            for (int j = 0; j < 4; ++j)
                acc[i][j] = __builtin_amdgcn_mfma_f32_16x16x32_f16(af[i], bfr[j], acc[i][j], 0, 0, 0);
        __syncthreads();
    }

#pragma unroll
    for (int i = 0; i < 4; ++i)
#pragma unroll
        for (int j = 0; j < 4; ++j) {
            int row = m0 + wm + i * 16 + q * 4;
            int col = n0 + wn + j * 16 + m16;
#pragma unroll
            for (int rix = 0; rix < 4; ++rix) {
                float v = acc[i][j][rix];
                size_t o = (size_t)(row + rix) * N + col;
                if constexpr (EPI == 0) {
                    outb[o] = (OT)gelu_f(v);
                } else {
                    outb[o] = (OT)(v + addsrc[o]);
                }
            }
        }
}

extern "C" void kernel_launch(void* const* d_in, const int* in_sizes, int n_in,
                              void* d_out, int out_size, void* d_ws, size_t ws_size,
                              hipStream_t stream) {
    const float* x    = (const float*)d_in[0];
    const float* rw   = (const float*)d_in[1];
    const int*   nf4  = (const int*)d_in[2];
    const float* mean = (const float*)d_in[3];
    const float* stdv = (const float*)d_in[4];
    const float* cb   = (const float*)d_in[5];
    const float* w1   = (const float*)d_in[6];
    const float* w2   = (const float*)d_in[7];
    float* out = (float*)d_out;   // reference output dtype is float32

    char* ws = (char*)d_ws;
    float* probs      = (float*)ws;                          // 128 KB
    float* moe        = (float*)(ws + 131072);               // 32 MB
    _Float16* xh      = (_Float16*)(ws + 33685504);          // 16 MB  [NTOK,H]
    _Float16* w1t     = (_Float16*)(ws + 50462720);          // 32 MB  [DFF,H]
    _Float16* w2t     = (_Float16*)(ws + 84017152);          // 32 MB  [H,DFF]
    _Float16* hid     = (_Float16*)(ws + 117571584);         // 64 MB  [NTOK,DFF]

    router_cast_kernel<<<NTOK, 256, 0, stream>>>(x, rw, probs, xh);
    transpose_cast_kernel<<<dim3(DFF / 32, H / 32), 256, 0, stream>>>(w1, w1t, H, DFF);
    transpose_cast_kernel<<<dim3(H / 32, DFF / 32), 256, 0, stream>>>(w2, w2t, DFF, H);
    moe_kernel<<<NTOK, 256, 0, stream>>>(nf4, mean, stdv, cb, probs, moe);
    // hidden = gelu(x @ w1):  A=xh [4096,2048], Bt=w1t [8192,2048]
    gemm_bt_kernel<0, _Float16><<<dim3(DFF / 128, NTOK / 128), 256, 0, stream>>>(xh, w1t, nullptr, hid, H, DFF);
    // out = moe + hidden @ w2: A=hid [4096,8192], Bt=w2t [2048,8192]
    gemm_bt_kernel<1, float><<<dim3(H / 128, NTOK / 128), 256, 0, stream>>>(hid, w2t, moe, out, DFF, H);
}

// Round 4
// 933.927 us; speedup vs baseline: 1.0016x; 1.0016x over previous
//
#include <hip/hip_runtime.h>
#include <hip/hip_bf16.h>
#include <hip/hip_fp16.h>

#define H 2048
#define E 8
#define DFF 8192
#define NTOK 4096
#define NB 4  // H/512 scale blocks

typedef _Float16 f16x8 __attribute__((ext_vector_type(8)));
typedef float f32x4 __attribute__((ext_vector_type(4)));

#define AS1 __attribute__((address_space(1)))
#define AS3 __attribute__((address_space(3)))

__device__ __forceinline__ void gl_lds16(const void* g, void* l) {
    __builtin_amdgcn_global_load_lds((const AS1 unsigned int*)g,
                                     (AS3 unsigned int*)l, 16, 0, 0);
}

__device__ __forceinline__ float gelu_f(float x) {
    // jax.nn.gelu approximate=True (tanh)
    float u = 0.7978845608028654f * x * (1.0f + 0.044715f * x * x);
    return 0.5f * x * (1.0f + tanhf(u));
}

// ---------------- router (fp32) + x -> fp16 cast ----------------
__global__ __launch_bounds__(256) void router_cast_kernel(
    const float* __restrict__ x, const float* __restrict__ rw,
    float* __restrict__ probs, _Float16* __restrict__ xh)
{
    int n = blockIdx.x, t = threadIdx.x;
    float acc[E];
#pragma unroll
    for (int e = 0; e < E; ++e) acc[e] = 0.f;
    const float* xr = x + (size_t)n * H;
#pragma unroll
    for (int k = 0; k < H / 256; ++k) {
        int h = t + k * 256;
        float xv = xr[h];
        xh[(size_t)n * H + h] = (_Float16)xv;
        const float4* r4 = reinterpret_cast<const float4*>(rw + (size_t)h * E);
        float4 a = r4[0], b = r4[1];
        acc[0] += xv * a.x; acc[1] += xv * a.y; acc[2] += xv * a.z; acc[3] += xv * a.w;
        acc[4] += xv * b.x; acc[5] += xv * b.y; acc[6] += xv * b.z; acc[7] += xv * b.w;
    }
#pragma unroll
    for (int e = 0; e < E; ++e) {
        float v = acc[e];
#pragma unroll
        for (int o = 32; o > 0; o >>= 1) v += __shfl_down(v, o, 64);
        acc[e] = v;
    }
    __shared__ float red[4][E];
    int wave = t >> 6, lane = t & 63;
    if (lane == 0) {
#pragma unroll
        for (int e = 0; e < E; ++e) red[wave][e] = acc[e];
    }
    __syncthreads();
    if (t == 0) {
        float lg[E];
        float mx = -1e30f;
#pragma unroll
        for (int e = 0; e < E; ++e) {
            lg[e] = red[0][e] + red[1][e] + red[2][e] + red[3][e];
            mx = fmaxf(mx, lg[e]);
        }
        float s = 0.f;
#pragma unroll
        for (int e = 0; e < E; ++e) { lg[e] = expf(lg[e] - mx); s += lg[e]; }
        float inv = 1.f / s;
#pragma unroll
        for (int e = 0; e < E; ++e) {
            float p = lg[e] * inv;
            p = __half2float(__float2half(p));  // fp16 round-trip as in reference
            probs[(size_t)n * E + e] = p;
        }
    }
}

// ---------------- transpose + cast fp32 [R,C] -> fp16 [C,R] ----------------
__global__ __launch_bounds__(256) void transpose_cast_kernel(
    const float* __restrict__ src, _Float16* __restrict__ dst, int R, int C)
{
    __shared__ float tile[32][33];
    int tx = threadIdx.x & 31, ty = threadIdx.x >> 5;
    int c0 = blockIdx.x * 32, r0 = blockIdx.y * 32;
#pragma unroll
    for (int i = ty; i < 32; i += 8)
        tile[i][tx] = src[(size_t)(r0 + i) * C + c0 + tx];
    __syncthreads();
#pragma unroll
    for (int i = ty; i < 32; i += 8)
        dst[(size_t)(c0 + i) * R + r0 + tx] = (_Float16)tile[tx][i];
}

// ---------------- NF4 dequant + expert mix -> moe (fp32) ----------------
__global__ __launch_bounds__(256) void moe_kernel(
    const int* __restrict__ nf4, const float* __restrict__ mean,
    const float* __restrict__ stdv, const float* __restrict__ cb,
    const float* __restrict__ probs, float* __restrict__ moe)
{
    int n = blockIdx.x, t = threadIdx.x;
    __shared__ float cbl[32];       // 2 copies of 16-entry codebook
    __shared__ float ps[E][NB];     // prob*std
    __shared__ float cmean[NB];     // sum_e prob*mean
    if (t < 16) { float v = cb[t]; cbl[t] = v; cbl[t + 16] = v; }
    else if (t >= 32 && t < 64) {
        int e = (t - 32) >> 2, b = t & 3;
        ps[e][b] = probs[(size_t)n * E + e] * stdv[((size_t)n * E + e) * NB + b];
    } else if (t >= 64 && t < 68) {
        int b = t - 64; float s = 0.f;
        for (int e = 0; e < E; ++e)
            s += probs[(size_t)n * E + e] * mean[((size_t)n * E + e) * NB + b];
        cmean[b] = s;
    }
    __syncthreads();
    int cboff = (t & 1) << 4;
    const int* w = nf4 + (size_t)n * (E * H / 2);
    float2* outp = reinterpret_cast<float2*>(moe + (size_t)n * H);
#pragma unroll
    for (int k = 0; k < 4; ++k) {    // b = (t + k*256)>>8 == k (wave-uniform)
        int j = t + k * 256;
        float psr[E];
#pragma unroll
        for (int e = 0; e < E; ++e) psr[e] = ps[e][k];
        float cm = cmean[k];
        float aL = cm, aH = cm;
#pragma unroll
        for (int e = 0; e < E; ++e) {
            int word = w[e * (H / 2) + j];
            aL += psr[e] * cbl[(word & 15) + cboff];
            aH += psr[e] * cbl[((word >> 4) & 15) + cboff];
        }
        outp[j] = make_float2(aL, aH);
    }
}

// ---------------- fp16 MFMA GEMM: C = A[M,K] * Bt[N,K]^T ----------------
// 1D grid, XCD supertile swizzle: xcd = id&7 owns an N-band of 2^bwShift
// x-blocks (keeps that band's B strips L2-resident); chunk sweeps x fast,
// y slow (A strip shared across the band, streamed once per y-row).
// EPI 0: out = f16(gelu(acc))        (hidden, ld=N, OT=_Float16)
// EPI 1: out = acc + addsrc          (final, ld=N, OT=float)
template <int EPI, typename OT>
__global__ __launch_bounds__(256, 4) void gemm_bt_kernel(
    const _Float16* __restrict__ A, const _Float16* __restrict__ Bt,
    const float* __restrict__ addsrc, OT* __restrict__ outb,
    int K, int N, int bwShift)
{
    __shared__ uint4 lds_u4[1024];   // 16 KB: A-tile [0,8192), B-tile [8192,16384)
    char* lds = (char*)lds_u4;

    int t = threadIdx.x;
    int id = blockIdx.x;
    int xcd = id & 7, chunk = id >> 3;
    int bx = (xcd << bwShift) | (chunk & ((1 << bwShift) - 1));
    int by = chunk >> bwShift;
    int m0 = by * 128, n0 = bx * 128;

    int r = t & 127, s0 = t >> 7;            // staging row / k-seg
    const unsigned short* pA = (const unsigned short*)A + (size_t)(m0 + r) * K + s0 * 8;
    const unsigned short* pB = (const unsigned short*)Bt + (size_t)(n0 + r) * K + s0 * 8;
    unsigned dst0 = (unsigned)t * 16, dst1 = (unsigned)t * 16 + 4096;

    int lane = t & 63, wave = t >> 6;
    int wm = (wave & 1) * 64, wn = (wave >> 1) * 64;
    int q = lane >> 4, m16 = lane & 15;

    unsigned aoff[4], boff[4];
#pragma unroll
    for (int i = 0; i < 4; ++i) aoff[i] = (unsigned)(q * 128 + wm + i * 16 + m16) * 16;
#pragma unroll
    for (int j = 0; j < 4; ++j) boff[j] = 8192u + (unsigned)(q * 128 + wn + j * 16 + m16) * 16;

    f32x4 acc[4][4] = {};

    for (int k0 = 0; k0 < K; k0 += 32) {
        gl_lds16(pA + k0,      lds + dst0);
        gl_lds16(pA + k0 + 16, lds + dst1);
        gl_lds16(pB + k0,      lds + 8192 + dst0);
        gl_lds16(pB + k0 + 16, lds + 8192 + dst1);
        __syncthreads();
        f16x8 af[4], bfr[4];
#pragma unroll
        for (int i = 0; i < 4; ++i) af[i] = *(const f16x8*)(lds + aoff[i]);
#pragma unroll
        for (int j = 0; j < 4; ++j) bfr[j] = *(const f16x8*)(lds + boff[j]);
#pragma unroll
        for (int i = 0; i < 4; ++i)
#pragma unroll
            for (int j = 0; j < 4; ++j)
                acc[i][j] = __builtin_amdgcn_mfma_f32_16x16x32_f16(af[i], bfr[j], acc[i][j], 0, 0, 0);
        __syncthreads();
    }

#pragma unroll
    for (int i = 0; i < 4; ++i)
#pragma unroll
        for (int j = 0; j < 4; ++j) {
            int row = m0 + wm + i * 16 + q * 4;
            int col = n0 + wn + j * 16 + m16;
#pragma unroll
            for (int rix = 0; rix < 4; ++rix) {
                float v = acc[i][j][rix];
                size_t o = (size_t)(row + rix) * N + col;
                if constexpr (EPI == 0) {
                    outb[o] = (OT)gelu_f(v);
                } else {
                    outb[o] = (OT)(v + addsrc[o]);
                }
            }
        }
}

extern "C" void kernel_launch(void* const* d_in, const int* in_sizes, int n_in,
                              void* d_out, int out_size, void* d_ws, size_t ws_size,
                              hipStream_t stream) {
    const float* x    = (const float*)d_in[0];
    const float* rw   = (const float*)d_in[1];
    const int*   nf4  = (const int*)d_in[2];
    const float* mean = (const float*)d_in[3];
    const float* stdv = (const float*)d_in[4];
    const float* cb   = (const float*)d_in[5];
    const float* w1   = (const float*)d_in[6];
    const float* w2   = (const float*)d_in[7];
    float* out = (float*)d_out;   // reference output dtype is float32

    char* ws = (char*)d_ws;
    float* probs      = (float*)ws;                          // 128 KB
    float* moe        = (float*)(ws + 131072);               // 32 MB
    _Float16* xh      = (_Float16*)(ws + 33685504);          // 16 MB  [NTOK,H]
    _Float16* w1t     = (_Float16*)(ws + 50462720);          // 32 MB  [DFF,H]
    _Float16* w2t     = (_Float16*)(ws + 84017152);          // 32 MB  [H,DFF]
    _Float16* hid     = (_Float16*)(ws + 117571584);         // 64 MB  [NTOK,DFF]

    router_cast_kernel<<<NTOK, 256, 0, stream>>>(x, rw, probs, xh);
    transpose_cast_kernel<<<dim3(DFF / 32, H / 32), 256, 0, stream>>>(w1, w1t, H, DFF);
    transpose_cast_kernel<<<dim3(H / 32, DFF / 32), 256, 0, stream>>>(w2, w2t, DFF, H);
    moe_kernel<<<NTOK, 256, 0, stream>>>(nf4, mean, stdv, cb, probs, moe);
    // hidden = gelu(x @ w1):  A=xh [4096,2048], Bt=w1t [8192,2048]
    //   grid 64x32 -> 1D 2048 blocks, band width 8 (bwShift=3)
    gemm_bt_kernel<0, _Float16><<<2048, 256, 0, stream>>>(xh, w1t, nullptr, hid, H, DFF, 3);
    // out = moe + hidden @ w2: A=hid [4096,8192], Bt=w2t [2048,8192]
    //   grid 16x32 -> 1D 512 blocks, band width 2 (bwShift=1)
    gemm_bt_kernel<1, float><<<512, 256, 0, stream>>>(hid, w2t, moe, out, DFF, H, 1);
}

// Round 5
// 922.069 us; speedup vs baseline: 1.0145x; 1.0129x over previous
//
#include <hip/hip_runtime.h>
#include <hip/hip_bf16.h>
#include <hip/hip_fp16.h>

#define H 2048
#define E 8
#define DFF 8192
#define NTOK 4096
#define NB 4  // H/512 scale blocks

typedef _Float16 f16x8 __attribute__((ext_vector_type(8)));
typedef float f32x4 __attribute__((ext_vector_type(4)));

#define AS1 __attribute__((address_space(1)))
#define AS3 __attribute__((address_space(3)))

__device__ __forceinline__ void gl_lds16(const void* g, void* l) {
    __builtin_amdgcn_global_load_lds((const AS1 unsigned int*)g,
                                     (AS3 unsigned int*)l, 16, 0, 0);
}

__device__ __forceinline__ float gelu_f(float x) {
    // jax.nn.gelu approximate=True (tanh)
    float u = 0.7978845608028654f * x * (1.0f + 0.044715f * x * x);
    return 0.5f * x * (1.0f + tanhf(u));
}

// ---------------- router (fp32) + x -> fp16 cast ----------------
__global__ __launch_bounds__(256) void router_cast_kernel(
    const float* __restrict__ x, const float* __restrict__ rw,
    float* __restrict__ probs, _Float16* __restrict__ xh)
{
    int n = blockIdx.x, t = threadIdx.x;
    float acc[E];
#pragma unroll
    for (int e = 0; e < E; ++e) acc[e] = 0.f;
    const float* xr = x + (size_t)n * H;
#pragma unroll
    for (int k = 0; k < H / 256; ++k) {
        int h = t + k * 256;
        float xv = xr[h];
        xh[(size_t)n * H + h] = (_Float16)xv;
        const float4* r4 = reinterpret_cast<const float4*>(rw + (size_t)h * E);
        float4 a = r4[0], b = r4[1];
        acc[0] += xv * a.x; acc[1] += xv * a.y; acc[2] += xv * a.z; acc[3] += xv * a.w;
        acc[4] += xv * b.x; acc[5] += xv * b.y; acc[6] += xv * b.z; acc[7] += xv * b.w;
    }
#pragma unroll
    for (int e = 0; e < E; ++e) {
        float v = acc[e];
#pragma unroll
        for (int o = 32; o > 0; o >>= 1) v += __shfl_down(v, o, 64);
        acc[e] = v;
    }
    __shared__ float red[4][E];
    int wave = t >> 6, lane = t & 63;
    if (lane == 0) {
#pragma unroll
        for (int e = 0; e < E; ++e) red[wave][e] = acc[e];
    }
    __syncthreads();
    if (t == 0) {
        float lg[E];
        float mx = -1e30f;
#pragma unroll
        for (int e = 0; e < E; ++e) {
            lg[e] = red[0][e] + red[1][e] + red[2][e] + red[3][e];
            mx = fmaxf(mx, lg[e]);
        }
        float s = 0.f;
#pragma unroll
        for (int e = 0; e < E; ++e) { lg[e] = expf(lg[e] - mx); s += lg[e]; }
        float inv = 1.f / s;
#pragma unroll
        for (int e = 0; e < E; ++e) {
            float p = lg[e] * inv;
            p = __half2float(__float2half(p));  // fp16 round-trip as in reference
            probs[(size_t)n * E + e] = p;
        }
    }
}

// ---------------- transpose + cast fp32 [R,C] -> fp16 [C,R] ----------------
__global__ __launch_bounds__(256) void transpose_cast_kernel(
    const float* __restrict__ src, _Float16* __restrict__ dst, int R, int C)
{
    __shared__ float tile[32][33];
    int tx = threadIdx.x & 31, ty = threadIdx.x >> 5;
    int c0 = blockIdx.x * 32, r0 = blockIdx.y * 32;
#pragma unroll
    for (int i = ty; i < 32; i += 8)
        tile[i][tx] = src[(size_t)(r0 + i) * C + c0 + tx];
    __syncthreads();
#pragma unroll
    for (int i = ty; i < 32; i += 8)
        dst[(size_t)(c0 + i) * R + r0 + tx] = (_Float16)tile[tx][i];
}

// ---------------- NF4 dequant + expert mix -> moe (fp32) ----------------
__global__ __launch_bounds__(256) void moe_kernel(
    const int* __restrict__ nf4, const float* __restrict__ mean,
    const float* __restrict__ stdv, const float* __restrict__ cb,
    const float* __restrict__ probs, float* __restrict__ moe)
{
    int n = blockIdx.x, t = threadIdx.x;
    __shared__ float cbl[32];       // 2 copies of 16-entry codebook
    __shared__ float ps[E][NB];     // prob*std
    __shared__ float cmean[NB];     // sum_e prob*mean
    if (t < 16) { float v = cb[t]; cbl[t] = v; cbl[t + 16] = v; }
    else if (t >= 32 && t < 64) {
        int e = (t - 32) >> 2, b = t & 3;
        ps[e][b] = probs[(size_t)n * E + e] * stdv[((size_t)n * E + e) * NB + b];
    } else if (t >= 64 && t < 68) {
        int b = t - 64; float s = 0.f;
        for (int e = 0; e < E; ++e)
            s += probs[(size_t)n * E + e] * mean[((size_t)n * E + e) * NB + b];
        cmean[b] = s;
    }
    __syncthreads();
    int cboff = (t & 1) << 4;
    const int* w = nf4 + (size_t)n * (E * H / 2);
    float2* outp = reinterpret_cast<float2*>(moe + (size_t)n * H);
#pragma unroll
    for (int k = 0; k < 4; ++k) {    // b = (t + k*256)>>8 == k (wave-uniform)
        int j = t + k * 256;
        float psr[E];
#pragma unroll
        for (int e = 0; e < E; ++e) psr[e] = ps[e][k];
        float cm = cmean[k];
        float aL = cm, aH = cm;
#pragma unroll
        for (int e = 0; e < E; ++e) {
            int word = w[e * (H / 2) + j];
            aL += psr[e] * cbl[(word & 15) + cboff];
            aH += psr[e] * cbl[((word >> 4) & 15) + cboff];
        }
        outp[j] = make_float2(aL, aH);
    }
}

// ---------------- fp16 MFMA GEMM: C = A[M,K] * Bt[N,K]^T ----------------
// Double-buffered LDS pipeline: prefetch tile k+1 into the alternate 16 KB
// buffer, then raw `s_waitcnt vmcnt(4)` + `s_barrier` — the 4 prefetch loads
// stay in flight across the barrier (hipBLASLt-style; never vmcnt(0) except
// the peeled last iteration). 1D grid with XCD supertile swizzle.
// EPI 0: out = f16(gelu(acc))        (hidden, ld=N, OT=_Float16)
// EPI 1: out = acc + addsrc          (final, ld=N, OT=float)
template <int EPI, typename OT>
__global__ __launch_bounds__(256, 4) void gemm_bt_kernel(
    const _Float16* __restrict__ A, const _Float16* __restrict__ Bt,
    const float* __restrict__ addsrc, OT* __restrict__ outb,
    int K, int N, int bwShift)
{
    __shared__ uint4 lds_u4[2048];   // 32 KB: buf0 [0,16K), buf1 [16K,32K)
    char* lds = (char*)lds_u4;

    int t = threadIdx.x;
    int id = blockIdx.x;
    int xcd = id & 7, chunk = id >> 3;
    int bx = (xcd << bwShift) | (chunk & ((1 << bwShift) - 1));
    int by = chunk >> bwShift;
    int m0 = by * 128, n0 = bx * 128;

    int r = t & 127, s0 = t >> 7;            // staging row / k-seg
    const unsigned short* pA = (const unsigned short*)A + (size_t)(m0 + r) * K + s0 * 8;
    const unsigned short* pB = (const unsigned short*)Bt + (size_t)(n0 + r) * K + s0 * 8;
    unsigned dst0 = (unsigned)t * 16, dst1 = (unsigned)t * 16 + 4096;

    int lane = t & 63, wave = t >> 6;
    int wm = (wave & 1) * 64, wn = (wave >> 1) * 64;
    int q = lane >> 4, m16 = lane & 15;

    unsigned aoff[4], boff[4];
#pragma unroll
    for (int i = 0; i < 4; ++i) aoff[i] = (unsigned)(q * 128 + wm + i * 16 + m16) * 16;
#pragma unroll
    for (int j = 0; j < 4; ++j) boff[j] = 8192u + (unsigned)(q * 128 + wn + j * 16 + m16) * 16;

    f32x4 acc[4][4] = {};

    // prologue: stage tile k=0 into buf0
    gl_lds16(pA,      lds + dst0);
    gl_lds16(pA + 16, lds + dst1);
    gl_lds16(pB,      lds + 8192 + dst0);
    gl_lds16(pB + 16, lds + 8192 + dst1);

    unsigned cur = 0;
    for (int k0 = 0; k0 < K; k0 += 32) {
        unsigned nxt = cur ^ 16384u;
        if (k0 + 32 < K) {
            // prefetch tile k0+32 into the alternate buffer (safe: barrier at
            // end of previous iteration guaranteed all reads of it finished)
            gl_lds16(pA + k0 + 32, lds + nxt + dst0);
            gl_lds16(pA + k0 + 48, lds + nxt + dst1);
            gl_lds16(pB + k0 + 32, lds + nxt + 8192 + dst0);
            gl_lds16(pB + k0 + 48, lds + nxt + 8192 + dst1);
            // wait only for the 4 OLDEST loads (current tile); prefetch stays in flight
            asm volatile("s_waitcnt vmcnt(4)" ::: "memory");
        } else {
            asm volatile("s_waitcnt vmcnt(0)" ::: "memory");
        }
        asm volatile("s_barrier" ::: "memory");

        f16x8 af[4], bfr[4];
#pragma unroll
        for (int i = 0; i < 4; ++i) af[i] = *(const f16x8*)(lds + cur + aoff[i]);
#pragma unroll
        for (int j = 0; j < 4; ++j) bfr[j] = *(const f16x8*)(lds + cur + boff[j]);
#pragma unroll
        for (int i = 0; i < 4; ++i)
#pragma unroll
            for (int j = 0; j < 4; ++j)
                acc[i][j] = __builtin_amdgcn_mfma_f32_16x16x32_f16(af[i], bfr[j], acc[i][j], 0, 0, 0);

        // protect `cur` before it becomes the prefetch target next iteration
        asm volatile("s_waitcnt lgkmcnt(0)" ::: "memory");
        asm volatile("s_barrier" ::: "memory");
        cur = nxt;
    }

#pragma unroll
    for (int i = 0; i < 4; ++i)
#pragma unroll
        for (int j = 0; j < 4; ++j) {
            int row = m0 + wm + i * 16 + q * 4;
            int col = n0 + wn + j * 16 + m16;
#pragma unroll
            for (int rix = 0; rix < 4; ++rix) {
                float v = acc[i][j][rix];
                size_t o = (size_t)(row + rix) * N + col;
                if constexpr (EPI == 0) {
                    outb[o] = (OT)gelu_f(v);
                } else {
                    outb[o] = (OT)(v + addsrc[o]);
                }
            }
        }
}

extern "C" void kernel_launch(void* const* d_in, const int* in_sizes, int n_in,
                              void* d_out, int out_size, void* d_ws, size_t ws_size,
                              hipStream_t stream) {
    const float* x    = (const float*)d_in[0];
    const float* rw   = (const float*)d_in[1];
    const int*   nf4  = (const int*)d_in[2];
    const float* mean = (const float*)d_in[3];
    const float* stdv = (const float*)d_in[4];
    const float* cb   = (const float*)d_in[5];
    const float* w1   = (const float*)d_in[6];
    const float* w2   = (const float*)d_in[7];
    float* out = (float*)d_out;   // reference output dtype is float32

    char* ws = (char*)d_ws;
    float* probs      = (float*)ws;                          // 128 KB
    float* moe        = (float*)(ws + 131072);               // 32 MB
    _Float16* xh      = (_Float16*)(ws + 33685504);          // 16 MB  [NTOK,H]
    _Float16* w1t     = (_Float16*)(ws + 50462720);          // 32 MB  [DFF,H]
    _Float16* w2t     = (_Float16*)(ws + 84017152);          // 32 MB  [H,DFF]
    _Float16* hid     = (_Float16*)(ws + 117571584);         // 64 MB  [NTOK,DFF]

    router_cast_kernel<<<NTOK, 256, 0, stream>>>(x, rw, probs, xh);
    transpose_cast_kernel<<<dim3(DFF / 32, H / 32), 256, 0, stream>>>(w1, w1t, H, DFF);
    transpose_cast_kernel<<<dim3(H / 32, DFF / 32), 256, 0, stream>>>(w2, w2t, DFF, H);
    moe_kernel<<<NTOK, 256, 0, stream>>>(nf4, mean, stdv, cb, probs, moe);
    // hidden = gelu(x @ w1):  A=xh [4096,2048], Bt=w1t [8192,2048]
    //   grid 64x32 -> 1D 2048 blocks, band width 8 (bwShift=3)
    gemm_bt_kernel<0, _Float16><<<2048, 256, 0, stream>>>(xh, w1t, nullptr, hid, H, DFF, 3);
    // out = moe + hidden @ w2: A=hid [4096,8192], Bt=w2t [2048,8192]
    //   grid 16x32 -> 1D 512 blocks, band width 2 (bwShift=1)
    gemm_bt_kernel<1, float><<<512, 256, 0, stream>>>(hid, w2t, moe, out, DFF, H, 1);
}

// Round 6
// 915.213 us; speedup vs baseline: 1.0221x; 1.0075x over previous
//
#include <hip/hip_runtime.h>
#include <hip/hip_bf16.h>
#include <hip/hip_fp16.h>

#define H 2048
#define E 8
#define DFF 8192
#define NTOK 4096
#define NB 4  // H/512 scale blocks

typedef _Float16 f16x8 __attribute__((ext_vector_type(8)));
typedef float f32x4 __attribute__((ext_vector_type(4)));

#define AS1 __attribute__((address_space(1)))
#define AS3 __attribute__((address_space(3)))

__device__ __forceinline__ void gl_lds16(const void* g, void* l) {
    __builtin_amdgcn_global_load_lds((const AS1 unsigned int*)g,
                                     (AS3 unsigned int*)l, 16, 0, 0);
}

__device__ __forceinline__ float gelu_f(float x) {
    // jax.nn.gelu approximate=True (tanh), with fast exp-based tanh:
    // tanh(t) = (1 - e^{-2t}) / (1 + e^{-2t}), t >= 0; sign restored.
    // __expf -> v_exp_f32 (single instr); underflow at large t gives exact +/-1.
    float u = 0.7978845608028654f * x * (1.0f + 0.044715f * x * x);
    float t = fabsf(u);
    float e = __expf(-2.0f * t);
    float th = (1.0f - e) / (1.0f + e);
    th = copysignf(th, u);
    return 0.5f * x * (1.0f + th);
}

// ---------------- router (fp32) + x -> fp16 cast ----------------
__global__ __launch_bounds__(256) void router_cast_kernel(
    const float* __restrict__ x, const float* __restrict__ rw,
    float* __restrict__ probs, _Float16* __restrict__ xh)
{
    int n = blockIdx.x, t = threadIdx.x;
    float acc[E];
#pragma unroll
    for (int e = 0; e < E; ++e) acc[e] = 0.f;
    const float* xr = x + (size_t)n * H;
#pragma unroll
    for (int k = 0; k < H / 256; ++k) {
        int h = t + k * 256;
        float xv = xr[h];
        xh[(size_t)n * H + h] = (_Float16)xv;
        const float4* r4 = reinterpret_cast<const float4*>(rw + (size_t)h * E);
        float4 a = r4[0], b = r4[1];
        acc[0] += xv * a.x; acc[1] += xv * a.y; acc[2] += xv * a.z; acc[3] += xv * a.w;
        acc[4] += xv * b.x; acc[5] += xv * b.y; acc[6] += xv * b.z; acc[7] += xv * b.w;
    }
#pragma unroll
    for (int e = 0; e < E; ++e) {
        float v = acc[e];
#pragma unroll
        for (int o = 32; o > 0; o >>= 1) v += __shfl_down(v, o, 64);
        acc[e] = v;
    }
    __shared__ float red[4][E];
    int wave = t >> 6, lane = t & 63;
    if (lane == 0) {
#pragma unroll
        for (int e = 0; e < E; ++e) red[wave][e] = acc[e];
    }
    __syncthreads();
    if (t == 0) {
        float lg[E];
        float mx = -1e30f;
#pragma unroll
        for (int e = 0; e < E; ++e) {
            lg[e] = red[0][e] + red[1][e] + red[2][e] + red[3][e];
            mx = fmaxf(mx, lg[e]);
        }
        float s = 0.f;
#pragma unroll
        for (int e = 0; e < E; ++e) { lg[e] = expf(lg[e] - mx); s += lg[e]; }
        float inv = 1.f / s;
#pragma unroll
        for (int e = 0; e < E; ++e) {
            float p = lg[e] * inv;
            p = __half2float(__float2half(p));  // fp16 round-trip as in reference
            probs[(size_t)n * E + e] = p;
        }
    }
}

// ---------------- transpose + cast fp32 [R,C] -> fp16 [C,R] ----------------
__global__ __launch_bounds__(256) void transpose_cast_kernel(
    const float* __restrict__ src, _Float16* __restrict__ dst, int R, int C)
{
    __shared__ float tile[32][33];
    int tx = threadIdx.x & 31, ty = threadIdx.x >> 5;
    int c0 = blockIdx.x * 32, r0 = blockIdx.y * 32;
#pragma unroll
    for (int i = ty; i < 32; i += 8)
        tile[i][tx] = src[(size_t)(r0 + i) * C + c0 + tx];
    __syncthreads();
#pragma unroll
    for (int i = ty; i < 32; i += 8)
        dst[(size_t)(c0 + i) * R + r0 + tx] = (_Float16)tile[tx][i];
}

// ---------------- NF4 dequant + expert mix -> moe (fp32) ----------------
__global__ __launch_bounds__(256) void moe_kernel(
    const int* __restrict__ nf4, const float* __restrict__ mean,
    const float* __restrict__ stdv, const float* __restrict__ cb,
    const float* __restrict__ probs, float* __restrict__ moe)
{
    int n = blockIdx.x, t = threadIdx.x;
    __shared__ float cbl[32];       // 2 copies of 16-entry codebook
    __shared__ float ps[E][NB];     // prob*std
    __shared__ float cmean[NB];     // sum_e prob*mean
    if (t < 16) { float v = cb[t]; cbl[t] = v; cbl[t + 16] = v; }
    else if (t >= 32 && t < 64) {
        int e = (t - 32) >> 2, b = t & 3;
        ps[e][b] = probs[(size_t)n * E + e] * stdv[((size_t)n * E + e) * NB + b];
    } else if (t >= 64 && t < 68) {
        int b = t - 64; float s = 0.f;
        for (int e = 0; e < E; ++e)
            s += probs[(size_t)n * E + e] * mean[((size_t)n * E + e) * NB + b];
        cmean[b] = s;
    }
    __syncthreads();
    int cboff = (t & 1) << 4;
    const int* w = nf4 + (size_t)n * (E * H / 2);
    float2* outp = reinterpret_cast<float2*>(moe + (size_t)n * H);
#pragma unroll
    for (int k = 0; k < 4; ++k) {    // b = (t + k*256)>>8 == k (wave-uniform)
        int j = t + k * 256;
        float psr[E];
#pragma unroll
        for (int e = 0; e < E; ++e) psr[e] = ps[e][k];
        float cm = cmean[k];
        float aL = cm, aH = cm;
#pragma unroll
        for (int e = 0; e < E; ++e) {
            int word = w[e * (H / 2) + j];
            aL += psr[e] * cbl[(word & 15) + cboff];
            aH += psr[e] * cbl[((word >> 4) & 15) + cboff];
        }
        outp[j] = make_float2(aL, aH);
    }
}

// ---------------- fp16 MFMA GEMM: C = A[M,K] * Bt[N,K]^T ----------------
// Double-buffered LDS pipeline: prefetch tile k+1 into the alternate 16 KB
// buffer, then raw `s_waitcnt vmcnt(4)` + `s_barrier` — the 4 prefetch loads
// stay in flight across the barrier (hipBLASLt-style; never vmcnt(0) except
// the peeled last iteration). 1D grid with XCD supertile swizzle.
// EPI 0: out = f16(gelu(acc))        (hidden, ld=N, OT=_Float16)
// EPI 1: out = acc + addsrc          (final, ld=N, OT=float)
template <int EPI, typename OT>
__global__ __launch_bounds__(256, 4) void gemm_bt_kernel(
    const _Float16* __restrict__ A, const _Float16* __restrict__ Bt,
    const float* __restrict__ addsrc, OT* __restrict__ outb,
    int K, int N, int bwShift)
{
    __shared__ uint4 lds_u4[2048];   // 32 KB: buf0 [0,16K), buf1 [16K,32K)
    char* lds = (char*)lds_u4;

    int t = threadIdx.x;
    int id = blockIdx.x;
    int xcd = id & 7, chunk = id >> 3;
    int bx = (xcd << bwShift) | (chunk & ((1 << bwShift) - 1));
    int by = chunk >> bwShift;
    int m0 = by * 128, n0 = bx * 128;

    int r = t & 127, s0 = t >> 7;            // staging row / k-seg
    const unsigned short* pA = (const unsigned short*)A + (size_t)(m0 + r) * K + s0 * 8;
    const unsigned short* pB = (const unsigned short*)Bt + (size_t)(n0 + r) * K + s0 * 8;
    unsigned dst0 = (unsigned)t * 16, dst1 = (unsigned)t * 16 + 4096;

    int lane = t & 63, wave = t >> 6;
    int wm = (wave & 1) * 64, wn = (wave >> 1) * 64;
    int q = lane >> 4, m16 = lane & 15;

    unsigned aoff[4], boff[4];
#pragma unroll
    for (int i = 0; i < 4; ++i) aoff[i] = (unsigned)(q * 128 + wm + i * 16 + m16) * 16;
#pragma unroll
    for (int j = 0; j < 4; ++j) boff[j] = 8192u + (unsigned)(q * 128 + wn + j * 16 + m16) * 16;

    f32x4 acc[4][4] = {};

    // prologue: stage tile k=0 into buf0
    gl_lds16(pA,      lds + dst0);
    gl_lds16(pA + 16, lds + dst1);
    gl_lds16(pB,      lds + 8192 + dst0);
    gl_lds16(pB + 16, lds + 8192 + dst1);

    unsigned cur = 0;
    for (int k0 = 0; k0 < K; k0 += 32) {
        unsigned nxt = cur ^ 16384u;
        if (k0 + 32 < K) {
            // prefetch tile k0+32 into the alternate buffer (safe: barrier at
            // end of previous iteration guaranteed all reads of it finished)
            gl_lds16(pA + k0 + 32, lds + nxt + dst0);
            gl_lds16(pA + k0 + 48, lds + nxt + dst1);
            gl_lds16(pB + k0 + 32, lds + nxt + 8192 + dst0);
            gl_lds16(pB + k0 + 48, lds + nxt + 8192 + dst1);
            // wait only for the 4 OLDEST loads (current tile); prefetch stays in flight
            asm volatile("s_waitcnt vmcnt(4)" ::: "memory");
        } else {
            asm volatile("s_waitcnt vmcnt(0)" ::: "memory");
        }
        asm volatile("s_barrier" ::: "memory");

        f16x8 af[4], bfr[4];
#pragma unroll
        for (int i = 0; i < 4; ++i) af[i] = *(const f16x8*)(lds + cur + aoff[i]);
#pragma unroll
        for (int j = 0; j < 4; ++j) bfr[j] = *(const f16x8*)(lds + cur + boff[j]);
#pragma unroll
        for (int i = 0; i < 4; ++i)
#pragma unroll
            for (int j = 0; j < 4; ++j)
                acc[i][j] = __builtin_amdgcn_mfma_f32_16x16x32_f16(af[i], bfr[j], acc[i][j], 0, 0, 0);

        // protect `cur` before it becomes the prefetch target next iteration
        asm volatile("s_waitcnt lgkmcnt(0)" ::: "memory");
        asm volatile("s_barrier" ::: "memory");
        cur = nxt;
    }

#pragma unroll
    for (int i = 0; i < 4; ++i)
#pragma unroll
        for (int j = 0; j < 4; ++j) {
            int row = m0 + wm + i * 16 + q * 4;
            int col = n0 + wn + j * 16 + m16;
#pragma unroll
            for (int rix = 0; rix < 4; ++rix) {
                float v = acc[i][j][rix];
                size_t o = (size_t)(row + rix) * N + col;
                if constexpr (EPI == 0) {
                    outb[o] = (OT)gelu_f(v);
                } else {
                    outb[o] = (OT)(v + addsrc[o]);
                }
            }
        }
}

extern "C" void kernel_launch(void* const* d_in, const int* in_sizes, int n_in,
                              void* d_out, int out_size, void* d_ws, size_t ws_size,
                              hipStream_t stream) {
    const float* x    = (const float*)d_in[0];
    const float* rw   = (const float*)d_in[1];
    const int*   nf4  = (const int*)d_in[2];
    const float* mean = (const float*)d_in[3];
    const float* stdv = (const float*)d_in[4];
    const float* cb   = (const float*)d_in[5];
    const float* w1   = (const float*)d_in[6];
    const float* w2   = (const float*)d_in[7];
    float* out = (float*)d_out;   // reference output dtype is float32

    char* ws = (char*)d_ws;
    float* probs      = (float*)ws;                          // 128 KB
    float* moe        = (float*)(ws + 131072);               // 32 MB
    _Float16* xh      = (_Float16*)(ws + 33685504);          // 16 MB  [NTOK,H]
    _Float16* w1t     = (_Float16*)(ws + 50462720);          // 32 MB  [DFF,H]
    _Float16* w2t     = (_Float16*)(ws + 84017152);          // 32 MB  [H,DFF]
    _Float16* hid     = (_Float16*)(ws + 117571584);         // 64 MB  [NTOK,DFF]

    router_cast_kernel<<<NTOK, 256, 0, stream>>>(x, rw, probs, xh);
    transpose_cast_kernel<<<dim3(DFF / 32, H / 32), 256, 0, stream>>>(w1, w1t, H, DFF);
    transpose_cast_kernel<<<dim3(H / 32, DFF / 32), 256, 0, stream>>>(w2, w2t, DFF, H);
    moe_kernel<<<NTOK, 256, 0, stream>>>(nf4, mean, stdv, cb, probs, moe);
    // hidden = gelu(x @ w1):  A=xh [4096,2048], Bt=w1t [8192,2048]
    //   grid 64x32 -> 1D 2048 blocks, band width 8 (bwShift=3)
    gemm_bt_kernel<0, _Float16><<<2048, 256, 0, stream>>>(xh, w1t, nullptr, hid, H, DFF, 3);
    // out = moe + hidden @ w2: A=hid [4096,8192], Bt=w2t [2048,8192]
    //   grid 16x32 -> 1D 512 blocks, band width 2 (bwShift=1)
    gemm_bt_kernel<1, float><<<512, 256, 0, stream>>>(hid, w2t, moe, out, DFF, H, 1);
}